// Round 5
// baseline (493.320 us; speedup 1.0000x reference)
//
#include <hip/hip_runtime.h>

#define NN 4096
#define FF 512
#define DD 64
#define HH 8
#define CC 40
#define HD (HH * DD)   // 512
#define CP 64          // padded class dim
#define MAXDEG 128
#define ALPHA 0.2f

#define L2BM 8
#define L2BK 32
#define MEGA_GRID 1024  // 4 blocks/CU x 256 CUs; guaranteed by launch_bounds(256,4)

typedef __attribute__((ext_vector_type(8))) short bf16x8;
typedef __attribute__((ext_vector_type(4))) float f32x4;

__device__ __forceinline__ float bf2f(unsigned short u) {
    union { unsigned int i; float f; } v;
    v.i = ((unsigned int)u) << 16;
    return v.f;
}

__device__ __forceinline__ unsigned short f2bf(float f) {
    union { float f; unsigned int u; } v;
    v.f = f;
    unsigned int r = v.u + 0x7fffu + ((v.u >> 16) & 1u);  // RNE
    return (unsigned short)(r >> 16);
}

__device__ __forceinline__ float wave_sum(float v) {
    #pragma unroll
    for (int off = 32; off; off >>= 1) v += __shfl_xor(v, off, 64);
    return v;
}

__device__ __forceinline__ float wave_max(float v) {
    #pragma unroll
    for (int off = 32; off; off >>= 1) v = fmaxf(v, __shfl_xor(v, off, 64));
    return v;
}

__device__ __forceinline__ float read_f(const void* src, int i, int isBf16) {
    if (isBf16) return bf2f(((const unsigned short*)src)[i]);
    return ((const float*)src)[i];
}

__device__ __forceinline__ int sniff_x(const void* xraw, int tid, int* fS) {
    if (tid == 0) *fS = 1;
    __syncthreads();
    int bad = 0;
    const unsigned int* xw = (const unsigned int*)xraw;
    #pragma unroll
    for (int q = 0; q < 4; q++) {
        unsigned int w = xw[(tid & 255) * 4 + q];
        unsigned int e0 = (w >> 7) & 0xffu;
        unsigned int e1 = (w >> 23) & 0xffu;
        if (e0 >= 0x90u || e1 >= 0x90u) bad = 1;
    }
    if (bad) *fS = 0;
    __syncthreads();
    return *fS;
}

// Device-scope grid barrier: monotonic counter, release/acquire threadfence
// (agent-scope fence emits the L2 writeback/invalidate required across the
// non-coherent per-XCD L2s). Correct only with all blocks co-resident —
// guaranteed by __launch_bounds__(256,4) + grid <= 4*256.
__device__ __forceinline__ void gbar(unsigned* bar, unsigned target) {
    __syncthreads();
    if (threadIdx.x == 0) {
        __threadfence();
        atomicAdd(bar, 1u);
        while (atomicAdd(bar, 0u) < target) __builtin_amdgcn_s_sleep(16);
        __threadfence();
    }
    __syncthreads();
}

// ---------------- prep: build_nbr + all conversions + bar reset -------------
__global__ __launch_bounds__(256) void prep(const unsigned char* __restrict__ adj,
                                            const void* __restrict__ x,
                                            const void* __restrict__ W1,
                                            const void* __restrict__ W2,
                                            const void* __restrict__ a1s,
                                            const void* __restrict__ a1d,
                                            const void* __restrict__ a2s,
                                            const void* __restrict__ a2d,
                                            int* __restrict__ nbr,
                                            int* __restrict__ deg,
                                            unsigned short* __restrict__ W1bth,
                                            unsigned short* __restrict__ W1btl,
                                            float* __restrict__ W2p,
                                            float* __restrict__ a1sf,
                                            float* __restrict__ a1df,
                                            float* __restrict__ a2sf,
                                            float* __restrict__ a2df,
                                            unsigned* __restrict__ bar) {
    __shared__ int cnt;
    __shared__ int fS;
    int t = threadIdx.x;
    int blk = blockIdx.x;
    if (blk == 0 && t == 0) *bar = 0u;  // reset mega's barrier each replay

    if (blk < NN) {
        if (t == 0) { cnt = 0; fS = 1; }
        __syncthreads();
        if (adj[(size_t)t * (NN + 1)] == 0) fS = 0;  // benign race
        __syncthreads();
        int isByte = fS;
        int i = blk;
        if (isByte) {
            uint4 v = ((const uint4*)(adj + (size_t)i * NN))[t];
            unsigned int u[4] = { v.x, v.y, v.z, v.w };
            int base = t * 16;
            #pragma unroll
            for (int q = 0; q < 4; q++) {
                #pragma unroll
                for (int b = 0; b < 4; b++) {
                    if ((u[q] >> (8 * b)) & 0xffu) {
                        int p = atomicAdd(&cnt, 1);
                        if (p < MAXDEG) nbr[(size_t)i * MAXDEG + p] = base + q * 4 + b;
                    }
                }
            }
        } else {
            const int4* row = (const int4*)((const int*)adj + (size_t)i * NN);
            #pragma unroll
            for (int q = 0; q < 4; q++) {
                int idx4 = q * 256 + t;
                int4 v = row[idx4];
                int base = idx4 * 4;
                if (v.x) { int p = atomicAdd(&cnt, 1); if (p < MAXDEG) nbr[(size_t)i * MAXDEG + p] = base; }
                if (v.y) { int p = atomicAdd(&cnt, 1); if (p < MAXDEG) nbr[(size_t)i * MAXDEG + p] = base + 1; }
                if (v.z) { int p = atomicAdd(&cnt, 1); if (p < MAXDEG) nbr[(size_t)i * MAXDEG + p] = base + 2; }
                if (v.w) { int p = atomicAdd(&cnt, 1); if (p < MAXDEG) nbr[(size_t)i * MAXDEG + p] = base + 3; }
            }
        }
        __syncthreads();
        if (t == 0) deg[i] = min(cnt, MAXDEG);
        return;
    }

    int bf = sniff_x(x, t, &fS);

    if (blk < NN + 64) {
        int b = blk - NN;                       // 0..63
        int ob = b * 4096 + t * 16;
        int row = ob >> 9;                      // hd*64 + d
        int f0 = ob & 511;
        int hd = row >> 6, d = row & 63;
        unsigned short hi[16], lo[16];
        #pragma unroll
        for (int q = 0; q < 16; q++) {
            float v = read_f(W1, (hd * FF + f0 + q) * DD + d, bf);
            unsigned short h16 = f2bf(v);
            hi[q] = h16;
            lo[q] = f2bf(v - bf2f(h16));
        }
        #pragma unroll
        for (int q = 0; q < 16; q++) {
            W1bth[(size_t)row * FF + f0 + q] = hi[q];
            W1btl[(size_t)row * FF + f0 + q] = lo[q];
        }
        return;
    }

    int i = (blk - NN - 64) * 256 + t;
    const int nW2p = HD * CP;          // 32,768
    const int nA1 = HD;                // 512
    if (i < nW2p) {
        int k = i / CP, c = i % CP;
        W2p[i] = (c < CC) ? read_f(W2, k * CC + c, bf) : 0.f;
        return;
    }
    i -= nW2p;
    if (i < nA1) { a1sf[i] = read_f(a1s, i, bf); return; }
    i -= nA1;
    if (i < nA1) { a1df[i] = read_f(a1d, i, bf); return; }
    i -= nA1;
    if (i < CC) { a2sf[i] = read_f(a2s, i, bf); return; }
    i -= CC;
    if (i < CC) { a2df[i] = read_f(a2d, i, bf); return; }
}

// LDS union across mega stages (max member 20,480 B)
union __align__(16) SharedU {
    struct { unsigned short Ah[64][40], Al[64][40], Bh[64][40], Bl[64][40]; } g1;
    struct { int js[MAXDEG]; float wls[HH][MAXDEG]; float invs[HH]; float4 red[128]; } a1;
    struct { float As[L2BK][L2BM + 1]; float Bs[L2BK][CP + 1]; } g2;
    struct { int js[4][MAXDEG]; float wls[4][MAXDEG]; } a2;
};

// ---- mega: l1_gemm -> bar -> l1_attn -> bar -> l2_fused -> bar -> l2_attn --
__global__ __launch_bounds__(256, 4) void mega(
        const void* __restrict__ xraw,
        const unsigned short* __restrict__ W1bth,
        const unsigned short* __restrict__ W1btl,
        const float* __restrict__ a1sf,
        const float* __restrict__ a1df,
        const int* __restrict__ nbr,
        const int* __restrict__ deg,
        unsigned short* __restrict__ hb,
        float* __restrict__ siv,
        float* __restrict__ sjv,
        float* __restrict__ x2,
        const float* __restrict__ W2p,
        const float* __restrict__ a2sf,
        const float* __restrict__ a2df,
        float* __restrict__ h2,
        float* __restrict__ d1,
        float* __restrict__ d2,
        float* __restrict__ out,
        unsigned* __restrict__ bar) {
    __shared__ SharedU su;
    __shared__ int fS;
    const int tid = threadIdx.x;
    const unsigned nb = gridDim.x;

    int isBf16 = sniff_x(xraw, tid, &fS);

    // ================= stage B: l1 GEMM (512 tiles) =================
    {
        int wave = tid >> 6, lane = tid & 63;
        int wm = wave >> 1, wn = wave & 1;
        int lr = lane & 15, lg = lane >> 4;
        int srow = tid >> 2, sseg = (tid & 3) * 8;

        for (int tile = blockIdx.x; tile < (NN / 64) * HH; tile += nb) {
            int bm = tile & 63, hd = tile >> 6;
            const unsigned short* wAp = W1bth + (size_t)(hd * 64 + srow) * FF + sseg;
            const unsigned short* wBp = W1btl + (size_t)(hd * 64 + srow) * FF + sseg;

            f32x4 acc[2][2];
            #pragma unroll
            for (int r = 0; r < 2; r++)
                #pragma unroll
                for (int c = 0; c < 2; c++) acc[r][c] = (f32x4){0.f, 0.f, 0.f, 0.f};

            if (isBf16) {
                const unsigned short* xp = (const unsigned short*)xraw
                                         + (size_t)(bm * 64 + srow) * FF + sseg;
                uint4 ra = *(const uint4*)xp;
                uint4 rb = *(const uint4*)wAp;
                for (int kk = 0; kk < FF; kk += 32) {
                    __syncthreads();
                    *(uint4*)&su.g1.Ah[srow][sseg] = ra;
                    *(uint4*)&su.g1.Bh[srow][sseg] = rb;
                    __syncthreads();
                    int kn = (kk + 32 < FF) ? kk + 32 : kk;
                    ra = *(const uint4*)(xp + kn);
                    rb = *(const uint4*)(wAp + kn);
                    bf16x8 a0 = *(const bf16x8*)&su.g1.Ah[wm * 32 + lr][lg * 8];
                    bf16x8 a1 = *(const bf16x8*)&su.g1.Ah[wm * 32 + 16 + lr][lg * 8];
                    bf16x8 b0 = *(const bf16x8*)&su.g1.Bh[wn * 32 + lr][lg * 8];
                    bf16x8 b1 = *(const bf16x8*)&su.g1.Bh[wn * 32 + 16 + lr][lg * 8];
                    acc[0][0] = __builtin_amdgcn_mfma_f32_16x16x32_bf16(a0, b0, acc[0][0], 0, 0, 0);
                    acc[0][1] = __builtin_amdgcn_mfma_f32_16x16x32_bf16(a0, b1, acc[0][1], 0, 0, 0);
                    acc[1][0] = __builtin_amdgcn_mfma_f32_16x16x32_bf16(a1, b0, acc[1][0], 0, 0, 0);
                    acc[1][1] = __builtin_amdgcn_mfma_f32_16x16x32_bf16(a1, b1, acc[1][1], 0, 0, 0);
                }
            } else {
                const float* xp = (const float*)xraw + (size_t)(bm * 64 + srow) * FF + sseg;
                float4 ra0 = *(const float4*)xp;
                float4 ra1 = *(const float4*)(xp + 4);
                uint4 rbh = *(const uint4*)wAp;
                uint4 rbl = *(const uint4*)wBp;
                for (int kk = 0; kk < FF; kk += 32) {
                    __syncthreads();
                    union { unsigned short s[8]; uint4 v; } uh, ul;
                    float fv[8] = { ra0.x, ra0.y, ra0.z, ra0.w, ra1.x, ra1.y, ra1.z, ra1.w };
                    #pragma unroll
                    for (int q = 0; q < 8; q++) {
                        unsigned short h16 = f2bf(fv[q]);
                        uh.s[q] = h16;
                        ul.s[q] = f2bf(fv[q] - bf2f(h16));
                    }
                    *(uint4*)&su.g1.Ah[srow][sseg] = uh.v;
                    *(uint4*)&su.g1.Al[srow][sseg] = ul.v;
                    *(uint4*)&su.g1.Bh[srow][sseg] = rbh;
                    *(uint4*)&su.g1.Bl[srow][sseg] = rbl;
                    __syncthreads();
                    int kn = (kk + 32 < FF) ? kk + 32 : kk;
                    ra0 = *(const float4*)(xp + kn);
                    ra1 = *(const float4*)(xp + kn + 4);
                    rbh = *(const uint4*)(wAp + kn);
                    rbl = *(const uint4*)(wBp + kn);

                    bf16x8 a_h0 = *(const bf16x8*)&su.g1.Ah[wm * 32 + lr][lg * 8];
                    bf16x8 a_h1 = *(const bf16x8*)&su.g1.Ah[wm * 32 + 16 + lr][lg * 8];
                    bf16x8 a_l0 = *(const bf16x8*)&su.g1.Al[wm * 32 + lr][lg * 8];
                    bf16x8 a_l1 = *(const bf16x8*)&su.g1.Al[wm * 32 + 16 + lr][lg * 8];
                    bf16x8 b_h0 = *(const bf16x8*)&su.g1.Bh[wn * 32 + lr][lg * 8];
                    bf16x8 b_h1 = *(const bf16x8*)&su.g1.Bh[wn * 32 + 16 + lr][lg * 8];
                    bf16x8 b_l0 = *(const bf16x8*)&su.g1.Bl[wn * 32 + lr][lg * 8];
                    bf16x8 b_l1 = *(const bf16x8*)&su.g1.Bl[wn * 32 + 16 + lr][lg * 8];

                    acc[0][0] = __builtin_amdgcn_mfma_f32_16x16x32_bf16(a_h0, b_h0, acc[0][0], 0, 0, 0);
                    acc[0][1] = __builtin_amdgcn_mfma_f32_16x16x32_bf16(a_h0, b_h1, acc[0][1], 0, 0, 0);
                    acc[1][0] = __builtin_amdgcn_mfma_f32_16x16x32_bf16(a_h1, b_h0, acc[1][0], 0, 0, 0);
                    acc[1][1] = __builtin_amdgcn_mfma_f32_16x16x32_bf16(a_h1, b_h1, acc[1][1], 0, 0, 0);
                    acc[0][0] = __builtin_amdgcn_mfma_f32_16x16x32_bf16(a_h0, b_l0, acc[0][0], 0, 0, 0);
                    acc[0][1] = __builtin_amdgcn_mfma_f32_16x16x32_bf16(a_h0, b_l1, acc[0][1], 0, 0, 0);
                    acc[1][0] = __builtin_amdgcn_mfma_f32_16x16x32_bf16(a_h1, b_l0, acc[1][0], 0, 0, 0);
                    acc[1][1] = __builtin_amdgcn_mfma_f32_16x16x32_bf16(a_h1, b_l1, acc[1][1], 0, 0, 0);
                    acc[0][0] = __builtin_amdgcn_mfma_f32_16x16x32_bf16(a_l0, b_h0, acc[0][0], 0, 0, 0);
                    acc[0][1] = __builtin_amdgcn_mfma_f32_16x16x32_bf16(a_l0, b_h1, acc[0][1], 0, 0, 0);
                    acc[1][0] = __builtin_amdgcn_mfma_f32_16x16x32_bf16(a_l1, b_h0, acc[1][0], 0, 0, 0);
                    acc[1][1] = __builtin_amdgcn_mfma_f32_16x16x32_bf16(a_l1, b_h1, acc[1][1], 0, 0, 0);
                }
            }

            // epilogue: h writes + si/sj partials (LDS reduce across wn waves)
            float adv[2], asv[2];
            #pragma unroll
            for (int fc = 0; fc < 2; fc++) {
                adv[fc] = a1df[hd * DD + wn * 32 + fc * 16 + lr];
                asv[fc] = a1sf[hd * DD + wn * 32 + fc * 16 + lr];
            }
            float pdv[2][4], psv[2][4];
            #pragma unroll
            for (int fr = 0; fr < 2; fr++) {
                #pragma unroll
                for (int q = 0; q < 4; q++) {
                    int row = bm * 64 + wm * 32 + fr * 16 + lg * 4 + q;
                    int colb = hd * 64 + wn * 32;
                    hb[(size_t)row * HD + colb + lr] = f2bf(acc[fr][0][q]);
                    hb[(size_t)row * HD + colb + 16 + lr] = f2bf(acc[fr][1][q]);
                    float pd = acc[fr][0][q] * adv[0] + acc[fr][1][q] * adv[1];
                    float ps = acc[fr][0][q] * asv[0] + acc[fr][1][q] * asv[1];
                    #pragma unroll
                    for (int off = 1; off < 16; off <<= 1) {
                        pd += __shfl_xor(pd, off, 64);
                        ps += __shfl_xor(ps, off, 64);
                    }
                    pdv[fr][q] = pd;
                    psv[fr][q] = ps;
                }
            }
            float* sred = (float*)&su.g1.Ah[0][0];
            __syncthreads();
            if (wn == 0 && lr == 0) {
                #pragma unroll
                for (int fr = 0; fr < 2; fr++)
                    #pragma unroll
                    for (int q = 0; q < 4; q++) {
                        int rl = wm * 32 + fr * 16 + lg * 4 + q;
                        sred[rl * 2] = pdv[fr][q];
                        sred[rl * 2 + 1] = psv[fr][q];
                    }
            }
            __syncthreads();
            if (wn == 1 && lr == 0) {
                #pragma unroll
                for (int fr = 0; fr < 2; fr++)
                    #pragma unroll
                    for (int q = 0; q < 4; q++) {
                        int rl = wm * 32 + fr * 16 + lg * 4 + q;
                        int row = bm * 64 + rl;
                        siv[(size_t)row * HH + hd] = sred[rl * 2] + pdv[fr][q];
                        sjv[(size_t)row * HH + hd] = sred[rl * 2 + 1] + psv[fr][q];
                    }
            }
            __syncthreads();  // protect sred reads before next tile's LDS writes
        }
    }
    gbar(bar, nb);

    // ================= stage C: l1 attention (4096 nodes) =================
    {
        int wave = tid >> 6, lane = tid & 63;
        int hd = wave * 2 + (lane >> 5);
        int l32 = lane & 31;
        int half = tid >> 7;
        int cq = tid & 127;
        for (int i = blockIdx.x; i < NN; i += nb) {
            int d = deg[i];
            for (int k = tid; k < d; k += 256) su.a1.js[k] = nbr[(size_t)i * MAXDEG + k];
            __syncthreads();

            float sii = siv[(size_t)i * HH + hd];
            float m = -1e30f;
            for (int k = l32; k < d; k += 32) {
                float sc = sii + sjv[(size_t)su.a1.js[k] * HH + hd];
                sc = sc > 0.f ? sc : ALPHA * sc;
                su.a1.wls[hd][k] = sc;
                m = fmaxf(m, sc);
            }
            #pragma unroll
            for (int off = 16; off; off >>= 1) m = fmaxf(m, __shfl_xor(m, off, 64));
            float s = 0.f;
            for (int k = l32; k < d; k += 32) {
                float e = expf(su.a1.wls[hd][k] - m);
                su.a1.wls[hd][k] = e;
                s += e;
            }
            #pragma unroll
            for (int off = 16; off; off >>= 1) s += __shfl_xor(s, off, 64);
            if (l32 == 0) su.a1.invs[hd] = 1.f / fmaxf(s, 1e-30f);
            __syncthreads();

            const uint2* hu2 = (const uint2*)hb;   // row stride HD/4 = 128
            const float* wl = su.a1.wls[cq >> 4];
            float a0 = 0.f, a1 = 0.f, a2 = 0.f, a3 = 0.f;
            int kk = half;
            for (; kk + 4 <= d; kk += 4) {
                uint2 v0 = hu2[(size_t)su.a1.js[kk] * 128 + cq];
                uint2 v1 = hu2[(size_t)su.a1.js[kk + 2] * 128 + cq];
                float w0 = wl[kk], w1 = wl[kk + 2];
                a0 = fmaf(w0, bf2f((unsigned short)v0.x), a0);
                a1 = fmaf(w0, bf2f((unsigned short)(v0.x >> 16)), a1);
                a2 = fmaf(w0, bf2f((unsigned short)v0.y), a2);
                a3 = fmaf(w0, bf2f((unsigned short)(v0.y >> 16)), a3);
                a0 = fmaf(w1, bf2f((unsigned short)v1.x), a0);
                a1 = fmaf(w1, bf2f((unsigned short)(v1.x >> 16)), a1);
                a2 = fmaf(w1, bf2f((unsigned short)v1.y), a2);
                a3 = fmaf(w1, bf2f((unsigned short)(v1.y >> 16)), a3);
            }
            for (; kk < d; kk += 2) {
                uint2 v = hu2[(size_t)su.a1.js[kk] * 128 + cq];
                float w = wl[kk];
                a0 = fmaf(w, bf2f((unsigned short)v.x), a0);
                a1 = fmaf(w, bf2f((unsigned short)(v.x >> 16)), a1);
                a2 = fmaf(w, bf2f((unsigned short)v.y), a2);
                a3 = fmaf(w, bf2f((unsigned short)(v.y >> 16)), a3);
            }
            if (half == 1) su.a1.red[cq] = make_float4(a0, a1, a2, a3);
            __syncthreads();
            if (half == 0) {
                float4 r = su.a1.red[cq];
                float inv = su.a1.invs[cq >> 4];
                a0 = (a0 + r.x) * inv;
                a1 = (a1 + r.y) * inv;
                a2 = (a2 + r.z) * inv;
                a3 = (a3 + r.w) * inv;
                float4 o;
                o.x = a0 > 0.f ? a0 : expm1f(a0);  // ELU fused
                o.y = a1 > 0.f ? a1 : expm1f(a1);
                o.z = a2 > 0.f ? a2 : expm1f(a2);
                o.w = a3 > 0.f ? a3 : expm1f(a3);
                *(float4*)(x2 + (size_t)i * HD + cq * 4) = o;
            }
            __syncthreads();  // protect red/invs/js before next node overwrites
        }
    }
    gbar(bar, 2u * nb);

    // ================= stage D: l2 GEMM + d1/d2 (512 tiles) =================
    {
        int ar = tid >> 5, ak = tid & 31;
        int br = tid >> 3, bc = (tid & 7) * 8;
        int c = tid & 63;
        int r0 = (tid >> 6) * 2;
        for (int bm = blockIdx.x; bm < NN / L2BM; bm += nb) {
            const float* Arow = x2 + (size_t)(bm * L2BM + ar) * FF;
            float acc0 = 0.f, acc1 = 0.f;
            float av = Arow[ak];
            float4 bv0 = *(const float4*)(W2p + (size_t)br * CP + bc);
            float4 bv1 = *(const float4*)(W2p + (size_t)br * CP + bc + 4);
            for (int kk = 0; kk < FF; kk += L2BK) {
                __syncthreads();
                su.g2.As[ak][ar] = av;
                *(float4*)&su.g2.Bs[br][bc] = bv0;
                *(float4*)&su.g2.Bs[br][bc + 4] = bv1;
                __syncthreads();
                int kn = (kk + L2BK < FF) ? kk + L2BK : kk;
                av = Arow[kn + ak];
                bv0 = *(const float4*)(W2p + (size_t)(kn + br) * CP + bc);
                bv1 = *(const float4*)(W2p + (size_t)(kn + br) * CP + bc + 4);
                #pragma unroll
                for (int k = 0; k < L2BK; k++) {
                    float b = su.g2.Bs[k][c];
                    acc0 = fmaf(su.g2.As[k][r0], b, acc0);
                    acc1 = fmaf(su.g2.As[k][r0 + 1], b, acc1);
                }
            }
            float accs[2] = { acc0, acc1 };
            float ad = (c < CC) ? a2df[c] : 0.f;
            float as = (c < CC) ? a2sf[c] : 0.f;
            #pragma unroll
            for (int q = 0; q < 2; q++) {
                int row = bm * L2BM + r0 + q;
                if (c < CC) h2[(size_t)row * CC + c] = accs[q];
                float pd = wave_sum(accs[q] * ad);
                float ps = wave_sum(accs[q] * as);
                if (c == 0) { d1[row] = pd; d2[row] = ps; }
            }
            __syncthreads();  // LDS reuse guard across tiles
        }
    }
    gbar(bar, 3u * nb);

    // ================= stage E: l2 attention (1024 groups) =================
    {
        int w = tid >> 6, lane = tid & 63;
        for (int g = blockIdx.x; g < NN / 4; g += nb) {
            int i = g * 4 + w;
            int d = deg[i];
            for (int k = lane; k < d; k += 64) su.a2.js[w][k] = nbr[(size_t)i * MAXDEG + k];

            float sii = d1[i];
            float m = -1e30f;
            for (int k = lane; k < d; k += 64) {
                float sc = sii + d2[su.a2.js[w][k]];
                sc = sc > 0.f ? sc : ALPHA * sc;
                su.a2.wls[w][k] = sc;
                m = fmaxf(m, sc);
            }
            m = wave_max(m);
            float s = 0.f;
            for (int k = lane; k < d; k += 64) {
                float e = expf(su.a2.wls[w][k] - m);
                su.a2.wls[w][k] = e;
                s += e;
            }
            s = fmaxf(wave_sum(s), 1e-30f);

            int c = lane;
            if (c < CC) {
                float acc = 0.f;
                int k = 0;
                for (; k + 4 <= d; k += 4) {
                    float v0 = h2[(size_t)su.a2.js[w][k] * CC + c];
                    float v1 = h2[(size_t)su.a2.js[w][k + 1] * CC + c];
                    float v2 = h2[(size_t)su.a2.js[w][k + 2] * CC + c];
                    float v3 = h2[(size_t)su.a2.js[w][k + 3] * CC + c];
                    acc = fmaf(su.a2.wls[w][k], v0, acc);
                    acc = fmaf(su.a2.wls[w][k + 1], v1, acc);
                    acc = fmaf(su.a2.wls[w][k + 2], v2, acc);
                    acc = fmaf(su.a2.wls[w][k + 3], v3, acc);
                }
                for (; k < d; k++)
                    acc = fmaf(su.a2.wls[w][k], h2[(size_t)su.a2.js[w][k] * CC + c], acc);
                out[(size_t)i * CC + c] = acc / s;
            }
            // per-wave LDS slices only -> no block sync needed between groups
        }
    }
}

extern "C" void kernel_launch(void* const* d_in, const int* in_sizes, int n_in,
                              void* d_out, int out_size, void* d_ws, size_t ws_size,
                              hipStream_t stream) {
    const void* x   = d_in[0];
    const unsigned char* adj = (const unsigned char*)d_in[1];
    const void* W1  = d_in[2];
    const void* a1s = d_in[3];  // a1_src
    const void* a1d = d_in[4];  // a1_dst
    const void* W2  = d_in[5];
    const void* a2s = d_in[6];
    const void* a2d = d_in[7];

    char* ws = (char*)d_ws;
    int*   nbr   = (int*)(ws + 0);                        // 2,097,152
    int*   deg   = (int*)(ws + 2097152);                  // 16,384
    float* siv   = (float*)(ws + 2113536);                // 131,072 [node][head]
    float* sjv   = (float*)(ws + 2244608);                // 131,072 [node][head]
    unsigned short* W1bth = (unsigned short*)(ws + 2375680);  // 524,288
    unsigned short* W1btl = (unsigned short*)(ws + 2899968);  // 524,288
    float* W2p   = (float*)(ws + 3424256);                // 131,072
    float* a1sf  = (float*)(ws + 3555328);                // 2,048
    float* a1df  = (float*)(ws + 3557376);                // 2,048
    float* a2sf  = (float*)(ws + 3559424);                // 256
    float* a2df  = (float*)(ws + 3559680);                // 256
    unsigned short* hb = (unsigned short*)(ws + 3559936); // 4,194,304 [N][H*D] bf16
    float* x2    = (float*)(ws + 7754240);                // 8,388,608
    float* h2    = (float*)(ws + 16142848);               // 655,360
    float* d1    = (float*)(ws + 16798208);               // 16,384
    float* d2    = (float*)(ws + 16814592);               // 16,384
    unsigned* bar = (unsigned*)(ws + 16830976);           // 4 (grid barrier)

    // R2: fixed overhead F ~= 98.5 us; pass ~= 69.5 us with 5 launches.
    // R4: fuse post-prep stages into one persistent kernel (3 device barriers
    // replace 3 launch boundaries); prep zeroes the barrier counter.
    const int nSmall = HD * CP + 2 * HD + 2 * CC;  // 33,872
    const int prepGrid = NN + 64 + (nSmall + 255) / 256;

    hipLaunchKernelGGL(prep, dim3(prepGrid), dim3(256), 0, stream,
                       adj, x, W1, W2, a1s, a1d, a2s, a2d,
                       nbr, deg, W1bth, W1btl, W2p, a1sf, a1df, a2sf, a2df, bar);
    hipLaunchKernelGGL(mega, dim3(MEGA_GRID), dim3(256), 0, stream,
                       x, W1bth, W1btl, a1sf, a1df, nbr, deg,
                       hb, siv, sjv, x2, W2p, a2sf, a2df, h2, d1, d2,
                       (float*)d_out, bar);
}

// Round 6
// 477.582 us; speedup vs baseline: 1.0330x; 1.0330x over previous
//
#include <hip/hip_runtime.h>

#define NN 4096
#define FF 512
#define DD 64
#define HH 8
#define CC 40
#define HD (HH * DD)   // 512
#define CP 64          // padded class dim
#define MAXDEG 128
#define ALPHA 0.2f

#define L2BM 8
#define L2BK 32
#define MEGA_GRID 1024  // 4 blocks/CU x 256 CUs; guaranteed by launch_bounds(256,4)

typedef __attribute__((ext_vector_type(8))) short bf16x8;
typedef __attribute__((ext_vector_type(4))) float f32x4;

__device__ __forceinline__ float bf2f(unsigned short u) {
    union { unsigned int i; float f; } v;
    v.i = ((unsigned int)u) << 16;
    return v.f;
}

__device__ __forceinline__ unsigned short f2bf(float f) {
    union { float f; unsigned int u; } v;
    v.f = f;
    unsigned int r = v.u + 0x7fffu + ((v.u >> 16) & 1u);  // RNE
    return (unsigned short)(r >> 16);
}

__device__ __forceinline__ float wave_sum(float v) {
    #pragma unroll
    for (int off = 32; off; off >>= 1) v += __shfl_xor(v, off, 64);
    return v;
}

__device__ __forceinline__ float wave_max(float v) {
    #pragma unroll
    for (int off = 32; off; off >>= 1) v = fmaxf(v, __shfl_xor(v, off, 64));
    return v;
}

__device__ __forceinline__ float read_f(const void* src, int i, int isBf16) {
    if (isBf16) return bf2f(((const unsigned short*)src)[i]);
    return ((const float*)src)[i];
}

__device__ __forceinline__ int sniff_x(const void* xraw, int tid, int* fS) {
    if (tid == 0) *fS = 1;
    __syncthreads();
    int bad = 0;
    const unsigned int* xw = (const unsigned int*)xraw;
    #pragma unroll
    for (int q = 0; q < 4; q++) {
        unsigned int w = xw[(tid & 255) * 4 + q];
        unsigned int e0 = (w >> 7) & 0xffu;
        unsigned int e1 = (w >> 23) & 0xffu;
        if (e0 >= 0x90u || e1 >= 0x90u) bad = 1;
    }
    if (bad) *fS = 0;
    __syncthreads();
    return *fS;
}

// Device-scope grid barrier. R5 fix (R4 post-mortem): pollers must NOT use
// RMW — 1024 atomicAdd(bar,0) pollers serialize at the fabric coherence
// point and arrival increments queue behind the poll storm (~100+ us/barrier,
// measured: mega 400 us @ 0.5% HBM, 4% VALU). Arrival = atomicAdd (RMW, 1024
// total). Poll = relaxed agent-scope atomic LOAD (scoped global_load bypasses
// the non-coherent per-XCD L2s; concurrent reads to one line don't serialize).
__device__ __forceinline__ void gbar(unsigned* bar, unsigned target) {
    __syncthreads();
    if (threadIdx.x == 0) {
        __threadfence();                 // release
        atomicAdd(bar, 1u);
        while (__hip_atomic_load(bar, __ATOMIC_RELAXED, __HIP_MEMORY_SCOPE_AGENT) < target)
            __builtin_amdgcn_s_sleep(32);
        __threadfence();                 // acquire
    }
    __syncthreads();
}

// ---------------- prep: build_nbr + all conversions + bar reset -------------
__global__ __launch_bounds__(256) void prep(const unsigned char* __restrict__ adj,
                                            const void* __restrict__ x,
                                            const void* __restrict__ W1,
                                            const void* __restrict__ W2,
                                            const void* __restrict__ a1s,
                                            const void* __restrict__ a1d,
                                            const void* __restrict__ a2s,
                                            const void* __restrict__ a2d,
                                            int* __restrict__ nbr,
                                            int* __restrict__ deg,
                                            unsigned short* __restrict__ W1bth,
                                            unsigned short* __restrict__ W1btl,
                                            float* __restrict__ W2p,
                                            float* __restrict__ a1sf,
                                            float* __restrict__ a1df,
                                            float* __restrict__ a2sf,
                                            float* __restrict__ a2df,
                                            unsigned* __restrict__ bar) {
    __shared__ int cnt;
    __shared__ int fS;
    int t = threadIdx.x;
    int blk = blockIdx.x;
    if (blk == 0 && t == 0) *bar = 0u;  // reset mega's barrier each replay

    if (blk < NN) {
        if (t == 0) { cnt = 0; fS = 1; }
        __syncthreads();
        if (adj[(size_t)t * (NN + 1)] == 0) fS = 0;  // benign race
        __syncthreads();
        int isByte = fS;
        int i = blk;
        if (isByte) {
            uint4 v = ((const uint4*)(adj + (size_t)i * NN))[t];
            unsigned int u[4] = { v.x, v.y, v.z, v.w };
            int base = t * 16;
            #pragma unroll
            for (int q = 0; q < 4; q++) {
                #pragma unroll
                for (int b = 0; b < 4; b++) {
                    if ((u[q] >> (8 * b)) & 0xffu) {
                        int p = atomicAdd(&cnt, 1);
                        if (p < MAXDEG) nbr[(size_t)i * MAXDEG + p] = base + q * 4 + b;
                    }
                }
            }
        } else {
            const int4* row = (const int4*)((const int*)adj + (size_t)i * NN);
            #pragma unroll
            for (int q = 0; q < 4; q++) {
                int idx4 = q * 256 + t;
                int4 v = row[idx4];
                int base = idx4 * 4;
                if (v.x) { int p = atomicAdd(&cnt, 1); if (p < MAXDEG) nbr[(size_t)i * MAXDEG + p] = base; }
                if (v.y) { int p = atomicAdd(&cnt, 1); if (p < MAXDEG) nbr[(size_t)i * MAXDEG + p] = base + 1; }
                if (v.z) { int p = atomicAdd(&cnt, 1); if (p < MAXDEG) nbr[(size_t)i * MAXDEG + p] = base + 2; }
                if (v.w) { int p = atomicAdd(&cnt, 1); if (p < MAXDEG) nbr[(size_t)i * MAXDEG + p] = base + 3; }
            }
        }
        __syncthreads();
        if (t == 0) deg[i] = min(cnt, MAXDEG);
        return;
    }

    int bf = sniff_x(x, t, &fS);

    if (blk < NN + 64) {
        int b = blk - NN;                       // 0..63
        int ob = b * 4096 + t * 16;
        int row = ob >> 9;                      // hd*64 + d
        int f0 = ob & 511;
        int hd = row >> 6, d = row & 63;
        unsigned short hi[16], lo[16];
        #pragma unroll
        for (int q = 0; q < 16; q++) {
            float v = read_f(W1, (hd * FF + f0 + q) * DD + d, bf);
            unsigned short h16 = f2bf(v);
            hi[q] = h16;
            lo[q] = f2bf(v - bf2f(h16));
        }
        #pragma unroll
        for (int q = 0; q < 16; q++) {
            W1bth[(size_t)row * FF + f0 + q] = hi[q];
            W1btl[(size_t)row * FF + f0 + q] = lo[q];
        }
        return;
    }

    int i = (blk - NN - 64) * 256 + t;
    const int nW2p = HD * CP;          // 32,768
    const int nA1 = HD;                // 512
    if (i < nW2p) {
        int k = i / CP, c = i % CP;
        W2p[i] = (c < CC) ? read_f(W2, k * CC + c, bf) : 0.f;
        return;
    }
    i -= nW2p;
    if (i < nA1) { a1sf[i] = read_f(a1s, i, bf); return; }
    i -= nA1;
    if (i < nA1) { a1df[i] = read_f(a1d, i, bf); return; }
    i -= nA1;
    if (i < CC) { a2sf[i] = read_f(a2s, i, bf); return; }
    i -= CC;
    if (i < CC) { a2df[i] = read_f(a2d, i, bf); return; }
}

// LDS union across mega stages (max member 20,480 B)
union __align__(16) SharedU {
    struct { unsigned short Ah[64][40], Al[64][40], Bh[64][40], Bl[64][40]; } g1;
    struct { int js[MAXDEG]; float wls[HH][MAXDEG]; float invs[HH]; float4 red[128]; } a1;
    struct { float As[L2BK][L2BM + 1]; float Bs[L2BK][CP + 1]; } g2;
    struct { int js[4][MAXDEG]; float wls[4][MAXDEG]; } a2;
};

// ---- mega: l1_gemm -> bar -> l1_attn -> bar -> l2_fused -> bar -> l2_attn --
__global__ __launch_bounds__(256, 4) void mega(
        const void* __restrict__ xraw,
        const unsigned short* __restrict__ W1bth,
        const unsigned short* __restrict__ W1btl,
        const float* __restrict__ a1sf,
        const float* __restrict__ a1df,
        const int* __restrict__ nbr,
        const int* __restrict__ deg,
        unsigned short* __restrict__ hb,
        float* __restrict__ siv,
        float* __restrict__ sjv,
        float* __restrict__ x2,
        const float* __restrict__ W2p,
        const float* __restrict__ a2sf,
        const float* __restrict__ a2df,
        float* __restrict__ h2,
        float* __restrict__ d1,
        float* __restrict__ d2,
        float* __restrict__ out,
        unsigned* __restrict__ bar) {
    __shared__ SharedU su;
    __shared__ int fS;
    const int tid = threadIdx.x;
    const unsigned nb = gridDim.x;

    int isBf16 = sniff_x(xraw, tid, &fS);

    // ================= stage B: l1 GEMM (512 tiles) =================
    {
        int wave = tid >> 6, lane = tid & 63;
        int wm = wave >> 1, wn = wave & 1;
        int lr = lane & 15, lg = lane >> 4;
        int srow = tid >> 2, sseg = (tid & 3) * 8;

        for (int tile = blockIdx.x; tile < (NN / 64) * HH; tile += nb) {
            int bm = tile & 63, hd = tile >> 6;
            const unsigned short* wAp = W1bth + (size_t)(hd * 64 + srow) * FF + sseg;
            const unsigned short* wBp = W1btl + (size_t)(hd * 64 + srow) * FF + sseg;

            f32x4 acc[2][2];
            #pragma unroll
            for (int r = 0; r < 2; r++)
                #pragma unroll
                for (int c = 0; c < 2; c++) acc[r][c] = (f32x4){0.f, 0.f, 0.f, 0.f};

            if (isBf16) {
                const unsigned short* xp = (const unsigned short*)xraw
                                         + (size_t)(bm * 64 + srow) * FF + sseg;
                uint4 ra = *(const uint4*)xp;
                uint4 rb = *(const uint4*)wAp;
                for (int kk = 0; kk < FF; kk += 32) {
                    __syncthreads();
                    *(uint4*)&su.g1.Ah[srow][sseg] = ra;
                    *(uint4*)&su.g1.Bh[srow][sseg] = rb;
                    __syncthreads();
                    int kn = (kk + 32 < FF) ? kk + 32 : kk;
                    ra = *(const uint4*)(xp + kn);
                    rb = *(const uint4*)(wAp + kn);
                    bf16x8 a0 = *(const bf16x8*)&su.g1.Ah[wm * 32 + lr][lg * 8];
                    bf16x8 a1 = *(const bf16x8*)&su.g1.Ah[wm * 32 + 16 + lr][lg * 8];
                    bf16x8 b0 = *(const bf16x8*)&su.g1.Bh[wn * 32 + lr][lg * 8];
                    bf16x8 b1 = *(const bf16x8*)&su.g1.Bh[wn * 32 + 16 + lr][lg * 8];
                    acc[0][0] = __builtin_amdgcn_mfma_f32_16x16x32_bf16(a0, b0, acc[0][0], 0, 0, 0);
                    acc[0][1] = __builtin_amdgcn_mfma_f32_16x16x32_bf16(a0, b1, acc[0][1], 0, 0, 0);
                    acc[1][0] = __builtin_amdgcn_mfma_f32_16x16x32_bf16(a1, b0, acc[1][0], 0, 0, 0);
                    acc[1][1] = __builtin_amdgcn_mfma_f32_16x16x32_bf16(a1, b1, acc[1][1], 0, 0, 0);
                }
            } else {
                const float* xp = (const float*)xraw + (size_t)(bm * 64 + srow) * FF + sseg;
                float4 ra0 = *(const float4*)xp;
                float4 ra1 = *(const float4*)(xp + 4);
                uint4 rbh = *(const uint4*)wAp;
                uint4 rbl = *(const uint4*)wBp;
                for (int kk = 0; kk < FF; kk += 32) {
                    __syncthreads();
                    union { unsigned short s[8]; uint4 v; } uh, ul;
                    float fv[8] = { ra0.x, ra0.y, ra0.z, ra0.w, ra1.x, ra1.y, ra1.z, ra1.w };
                    #pragma unroll
                    for (int q = 0; q < 8; q++) {
                        unsigned short h16 = f2bf(fv[q]);
                        uh.s[q] = h16;
                        ul.s[q] = f2bf(fv[q] - bf2f(h16));
                    }
                    *(uint4*)&su.g1.Ah[srow][sseg] = uh.v;
                    *(uint4*)&su.g1.Al[srow][sseg] = ul.v;
                    *(uint4*)&su.g1.Bh[srow][sseg] = rbh;
                    *(uint4*)&su.g1.Bl[srow][sseg] = rbl;
                    __syncthreads();
                    int kn = (kk + 32 < FF) ? kk + 32 : kk;
                    ra0 = *(const float4*)(xp + kn);
                    ra1 = *(const float4*)(xp + kn + 4);
                    rbh = *(const uint4*)(wAp + kn);
                    rbl = *(const uint4*)(wBp + kn);

                    bf16x8 a_h0 = *(const bf16x8*)&su.g1.Ah[wm * 32 + lr][lg * 8];
                    bf16x8 a_h1 = *(const bf16x8*)&su.g1.Ah[wm * 32 + 16 + lr][lg * 8];
                    bf16x8 a_l0 = *(const bf16x8*)&su.g1.Al[wm * 32 + lr][lg * 8];
                    bf16x8 a_l1 = *(const bf16x8*)&su.g1.Al[wm * 32 + 16 + lr][lg * 8];
                    bf16x8 b_h0 = *(const bf16x8*)&su.g1.Bh[wn * 32 + lr][lg * 8];
                    bf16x8 b_h1 = *(const bf16x8*)&su.g1.Bh[wn * 32 + 16 + lr][lg * 8];
                    bf16x8 b_l0 = *(const bf16x8*)&su.g1.Bl[wn * 32 + lr][lg * 8];
                    bf16x8 b_l1 = *(const bf16x8*)&su.g1.Bl[wn * 32 + 16 + lr][lg * 8];

                    acc[0][0] = __builtin_amdgcn_mfma_f32_16x16x32_bf16(a_h0, b_h0, acc[0][0], 0, 0, 0);
                    acc[0][1] = __builtin_amdgcn_mfma_f32_16x16x32_bf16(a_h0, b_h1, acc[0][1], 0, 0, 0);
                    acc[1][0] = __builtin_amdgcn_mfma_f32_16x16x32_bf16(a_h1, b_h0, acc[1][0], 0, 0, 0);
                    acc[1][1] = __builtin_amdgcn_mfma_f32_16x16x32_bf16(a_h1, b_h1, acc[1][1], 0, 0, 0);
                    acc[0][0] = __builtin_amdgcn_mfma_f32_16x16x32_bf16(a_h0, b_l0, acc[0][0], 0, 0, 0);
                    acc[0][1] = __builtin_amdgcn_mfma_f32_16x16x32_bf16(a_h0, b_l1, acc[0][1], 0, 0, 0);
                    acc[1][0] = __builtin_amdgcn_mfma_f32_16x16x32_bf16(a_h1, b_l0, acc[1][0], 0, 0, 0);
                    acc[1][1] = __builtin_amdgcn_mfma_f32_16x16x32_bf16(a_h1, b_l1, acc[1][1], 0, 0, 0);
                    acc[0][0] = __builtin_amdgcn_mfma_f32_16x16x32_bf16(a_l0, b_h0, acc[0][0], 0, 0, 0);
                    acc[0][1] = __builtin_amdgcn_mfma_f32_16x16x32_bf16(a_l0, b_h1, acc[0][1], 0, 0, 0);
                    acc[1][0] = __builtin_amdgcn_mfma_f32_16x16x32_bf16(a_l1, b_h0, acc[1][0], 0, 0, 0);
                    acc[1][1] = __builtin_amdgcn_mfma_f32_16x16x32_bf16(a_l1, b_h1, acc[1][1], 0, 0, 0);
                }
            }

            // epilogue: h writes + si/sj partials (LDS reduce across wn waves)
            float adv[2], asv[2];
            #pragma unroll
            for (int fc = 0; fc < 2; fc++) {
                adv[fc] = a1df[hd * DD + wn * 32 + fc * 16 + lr];
                asv[fc] = a1sf[hd * DD + wn * 32 + fc * 16 + lr];
            }
            float pdv[2][4], psv[2][4];
            #pragma unroll
            for (int fr = 0; fr < 2; fr++) {
                #pragma unroll
                for (int q = 0; q < 4; q++) {
                    int row = bm * 64 + wm * 32 + fr * 16 + lg * 4 + q;
                    int colb = hd * 64 + wn * 32;
                    hb[(size_t)row * HD + colb + lr] = f2bf(acc[fr][0][q]);
                    hb[(size_t)row * HD + colb + 16 + lr] = f2bf(acc[fr][1][q]);
                    float pd = acc[fr][0][q] * adv[0] + acc[fr][1][q] * adv[1];
                    float ps = acc[fr][0][q] * asv[0] + acc[fr][1][q] * asv[1];
                    #pragma unroll
                    for (int off = 1; off < 16; off <<= 1) {
                        pd += __shfl_xor(pd, off, 64);
                        ps += __shfl_xor(ps, off, 64);
                    }
                    pdv[fr][q] = pd;
                    psv[fr][q] = ps;
                }
            }
            float* sred = (float*)&su.g1.Ah[0][0];
            __syncthreads();
            if (wn == 0 && lr == 0) {
                #pragma unroll
                for (int fr = 0; fr < 2; fr++)
                    #pragma unroll
                    for (int q = 0; q < 4; q++) {
                        int rl = wm * 32 + fr * 16 + lg * 4 + q;
                        sred[rl * 2] = pdv[fr][q];
                        sred[rl * 2 + 1] = psv[fr][q];
                    }
            }
            __syncthreads();
            if (wn == 1 && lr == 0) {
                #pragma unroll
                for (int fr = 0; fr < 2; fr++)
                    #pragma unroll
                    for (int q = 0; q < 4; q++) {
                        int rl = wm * 32 + fr * 16 + lg * 4 + q;
                        int row = bm * 64 + rl;
                        siv[(size_t)row * HH + hd] = sred[rl * 2] + pdv[fr][q];
                        sjv[(size_t)row * HH + hd] = sred[rl * 2 + 1] + psv[fr][q];
                    }
            }
            __syncthreads();  // protect sred reads before next tile's LDS writes
        }
    }
    gbar(bar, nb);

    // ================= stage C: l1 attention (4096 nodes) =================
    {
        int wave = tid >> 6, lane = tid & 63;
        int hd = wave * 2 + (lane >> 5);
        int l32 = lane & 31;
        int half = tid >> 7;
        int cq = tid & 127;
        for (int i = blockIdx.x; i < NN; i += nb) {
            int d = deg[i];
            for (int k = tid; k < d; k += 256) su.a1.js[k] = nbr[(size_t)i * MAXDEG + k];
            __syncthreads();

            float sii = siv[(size_t)i * HH + hd];
            float m = -1e30f;
            for (int k = l32; k < d; k += 32) {
                float sc = sii + sjv[(size_t)su.a1.js[k] * HH + hd];
                sc = sc > 0.f ? sc : ALPHA * sc;
                su.a1.wls[hd][k] = sc;
                m = fmaxf(m, sc);
            }
            #pragma unroll
            for (int off = 16; off; off >>= 1) m = fmaxf(m, __shfl_xor(m, off, 64));
            float s = 0.f;
            for (int k = l32; k < d; k += 32) {
                float e = expf(su.a1.wls[hd][k] - m);
                su.a1.wls[hd][k] = e;
                s += e;
            }
            #pragma unroll
            for (int off = 16; off; off >>= 1) s += __shfl_xor(s, off, 64);
            if (l32 == 0) su.a1.invs[hd] = 1.f / fmaxf(s, 1e-30f);
            __syncthreads();

            const uint2* hu2 = (const uint2*)hb;   // row stride HD/4 = 128
            const float* wl = su.a1.wls[cq >> 4];
            float a0 = 0.f, a1 = 0.f, a2 = 0.f, a3 = 0.f;
            int kk = half;
            for (; kk + 4 <= d; kk += 4) {
                uint2 v0 = hu2[(size_t)su.a1.js[kk] * 128 + cq];
                uint2 v1 = hu2[(size_t)su.a1.js[kk + 2] * 128 + cq];
                float w0 = wl[kk], w1 = wl[kk + 2];
                a0 = fmaf(w0, bf2f((unsigned short)v0.x), a0);
                a1 = fmaf(w0, bf2f((unsigned short)(v0.x >> 16)), a1);
                a2 = fmaf(w0, bf2f((unsigned short)v0.y), a2);
                a3 = fmaf(w0, bf2f((unsigned short)(v0.y >> 16)), a3);
                a0 = fmaf(w1, bf2f((unsigned short)v1.x), a0);
                a1 = fmaf(w1, bf2f((unsigned short)(v1.x >> 16)), a1);
                a2 = fmaf(w1, bf2f((unsigned short)v1.y), a2);
                a3 = fmaf(w1, bf2f((unsigned short)(v1.y >> 16)), a3);
            }
            for (; kk < d; kk += 2) {
                uint2 v = hu2[(size_t)su.a1.js[kk] * 128 + cq];
                float w = wl[kk];
                a0 = fmaf(w, bf2f((unsigned short)v.x), a0);
                a1 = fmaf(w, bf2f((unsigned short)(v.x >> 16)), a1);
                a2 = fmaf(w, bf2f((unsigned short)v.y), a2);
                a3 = fmaf(w, bf2f((unsigned short)(v.y >> 16)), a3);
            }
            if (half == 1) su.a1.red[cq] = make_float4(a0, a1, a2, a3);
            __syncthreads();
            if (half == 0) {
                float4 r = su.a1.red[cq];
                float inv = su.a1.invs[cq >> 4];
                a0 = (a0 + r.x) * inv;
                a1 = (a1 + r.y) * inv;
                a2 = (a2 + r.z) * inv;
                a3 = (a3 + r.w) * inv;
                float4 o;
                o.x = a0 > 0.f ? a0 : expm1f(a0);  // ELU fused
                o.y = a1 > 0.f ? a1 : expm1f(a1);
                o.z = a2 > 0.f ? a2 : expm1f(a2);
                o.w = a3 > 0.f ? a3 : expm1f(a3);
                *(float4*)(x2 + (size_t)i * HD + cq * 4) = o;
            }
            __syncthreads();  // protect red/invs/js before next node overwrites
        }
    }
    gbar(bar, 2u * nb);

    // ================= stage D: l2 GEMM + d1/d2 (512 tiles) =================
    {
        int ar = tid >> 5, ak = tid & 31;
        int br = tid >> 3, bc = (tid & 7) * 8;
        int c = tid & 63;
        int r0 = (tid >> 6) * 2;
        for (int bm = blockIdx.x; bm < NN / L2BM; bm += nb) {
            const float* Arow = x2 + (size_t)(bm * L2BM + ar) * FF;
            float acc0 = 0.f, acc1 = 0.f;
            float av = Arow[ak];
            float4 bv0 = *(const float4*)(W2p + (size_t)br * CP + bc);
            float4 bv1 = *(const float4*)(W2p + (size_t)br * CP + bc + 4);
            for (int kk = 0; kk < FF; kk += L2BK) {
                __syncthreads();
                su.g2.As[ak][ar] = av;
                *(float4*)&su.g2.Bs[br][bc] = bv0;
                *(float4*)&su.g2.Bs[br][bc + 4] = bv1;
                __syncthreads();
                int kn = (kk + L2BK < FF) ? kk + L2BK : kk;
                av = Arow[kn + ak];
                bv0 = *(const float4*)(W2p + (size_t)(kn + br) * CP + bc);
                bv1 = *(const float4*)(W2p + (size_t)(kn + br) * CP + bc + 4);
                #pragma unroll
                for (int k = 0; k < L2BK; k++) {
                    float b = su.g2.Bs[k][c];
                    acc0 = fmaf(su.g2.As[k][r0], b, acc0);
                    acc1 = fmaf(su.g2.As[k][r0 + 1], b, acc1);
                }
            }
            float accs[2] = { acc0, acc1 };
            float ad = (c < CC) ? a2df[c] : 0.f;
            float as = (c < CC) ? a2sf[c] : 0.f;
            #pragma unroll
            for (int q = 0; q < 2; q++) {
                int row = bm * L2BM + r0 + q;
                if (c < CC) h2[(size_t)row * CC + c] = accs[q];
                float pd = wave_sum(accs[q] * ad);
                float ps = wave_sum(accs[q] * as);
                if (c == 0) { d1[row] = pd; d2[row] = ps; }
            }
            __syncthreads();  // LDS reuse guard across tiles
        }
    }
    gbar(bar, 3u * nb);

    // ================= stage E: l2 attention (1024 groups) =================
    {
        int w = tid >> 6, lane = tid & 63;
        for (int g = blockIdx.x; g < NN / 4; g += nb) {
            int i = g * 4 + w;
            int d = deg[i];
            for (int k = lane; k < d; k += 64) su.a2.js[w][k] = nbr[(size_t)i * MAXDEG + k];

            float sii = d1[i];
            float m = -1e30f;
            for (int k = lane; k < d; k += 64) {
                float sc = sii + d2[su.a2.js[w][k]];
                sc = sc > 0.f ? sc : ALPHA * sc;
                su.a2.wls[w][k] = sc;
                m = fmaxf(m, sc);
            }
            m = wave_max(m);
            float s = 0.f;
            for (int k = lane; k < d; k += 64) {
                float e = expf(su.a2.wls[w][k] - m);
                su.a2.wls[w][k] = e;
                s += e;
            }
            s = fmaxf(wave_sum(s), 1e-30f);

            int c = lane;
            if (c < CC) {
                float acc = 0.f;
                int k = 0;
                for (; k + 4 <= d; k += 4) {
                    float v0 = h2[(size_t)su.a2.js[w][k] * CC + c];
                    float v1 = h2[(size_t)su.a2.js[w][k + 1] * CC + c];
                    float v2 = h2[(size_t)su.a2.js[w][k + 2] * CC + c];
                    float v3 = h2[(size_t)su.a2.js[w][k + 3] * CC + c];
                    acc = fmaf(su.a2.wls[w][k], v0, acc);
                    acc = fmaf(su.a2.wls[w][k + 1], v1, acc);
                    acc = fmaf(su.a2.wls[w][k + 2], v2, acc);
                    acc = fmaf(su.a2.wls[w][k + 3], v3, acc);
                }
                for (; k < d; k++)
                    acc = fmaf(su.a2.wls[w][k], h2[(size_t)su.a2.js[w][k] * CC + c], acc);
                out[(size_t)i * CC + c] = acc / s;
            }
            // per-wave LDS slices only -> no block sync needed between groups
        }
    }
}

extern "C" void kernel_launch(void* const* d_in, const int* in_sizes, int n_in,
                              void* d_out, int out_size, void* d_ws, size_t ws_size,
                              hipStream_t stream) {
    const void* x   = d_in[0];
    const unsigned char* adj = (const unsigned char*)d_in[1];
    const void* W1  = d_in[2];
    const void* a1s = d_in[3];  // a1_src
    const void* a1d = d_in[4];  // a1_dst
    const void* W2  = d_in[5];
    const void* a2s = d_in[6];
    const void* a2d = d_in[7];

    char* ws = (char*)d_ws;
    int*   nbr   = (int*)(ws + 0);                        // 2,097,152
    int*   deg   = (int*)(ws + 2097152);                  // 16,384
    float* siv   = (float*)(ws + 2113536);                // 131,072 [node][head]
    float* sjv   = (float*)(ws + 2244608);                // 131,072 [node][head]
    unsigned short* W1bth = (unsigned short*)(ws + 2375680);  // 524,288
    unsigned short* W1btl = (unsigned short*)(ws + 2899968);  // 524,288
    float* W2p   = (float*)(ws + 3424256);                // 131,072
    float* a1sf  = (float*)(ws + 3555328);                // 2,048
    float* a1df  = (float*)(ws + 3557376);                // 2,048
    float* a2sf  = (float*)(ws + 3559424);                // 256
    float* a2df  = (float*)(ws + 3559680);                // 256
    unsigned short* hb = (unsigned short*)(ws + 3559936); // 4,194,304 [N][H*D] bf16
    float* x2    = (float*)(ws + 7754240);                // 8,388,608
    float* h2    = (float*)(ws + 16142848);               // 655,360
    float* d1    = (float*)(ws + 16798208);               // 16,384
    float* d2    = (float*)(ws + 16814592);               // 16,384
    unsigned* bar = (unsigned*)(ws + 16830976);           // 4 (grid barrier)

    // R5: identical to R4 except gbar polls with relaxed agent-scope atomic
    // LOAD (no RMW) — R4's atomicAdd(bar,0) poll storm serialized arrivals
    // at the fabric coherence point (mega 400 us @ 0.5% HBM / 4% VALU).
    const int nSmall = HD * CP + 2 * HD + 2 * CC;  // 33,872
    const int prepGrid = NN + 64 + (nSmall + 255) / 256;

    hipLaunchKernelGGL(prep, dim3(prepGrid), dim3(256), 0, stream,
                       adj, x, W1, W2, a1s, a1d, a2s, a2d,
                       nbr, deg, W1bth, W1btl, W2p, a1sf, a1df, a2sf, a2df, bar);
    hipLaunchKernelGGL(mega, dim3(MEGA_GRID), dim3(256), 0, stream,
                       x, W1bth, W1btl, a1sf, a1df, nbr, deg,
                       hb, siv, sjv, x2, W2p, a2sf, a2df, h2, d1, d2,
                       (float*)d_out, bar);
}

// Round 7
// 161.644 us; speedup vs baseline: 3.0519x; 2.9545x over previous
//
#include <hip/hip_runtime.h>

#define NN 4096
#define FF 512
#define DD 64
#define HH 8
#define CC 40
#define HD (HH * DD)   // 512
#define CP 64          // padded class dim
#define MAXDEG 128
#define ALPHA 0.2f

// f32 GEMM tiling (l2)
#define BM 64
#define BN 64
#define BK 16
#define SK2 8
#define KH2 (FF / SK2) // 64 per split

typedef __attribute__((ext_vector_type(8))) short bf16x8;
typedef __attribute__((ext_vector_type(4))) float f32x4;

__device__ __forceinline__ float bf2f(unsigned short u) {
    union { unsigned int i; float f; } v;
    v.i = ((unsigned int)u) << 16;
    return v.f;
}

__device__ __forceinline__ unsigned short f2bf(float f) {
    union { float f; unsigned int u; } v;
    v.f = f;
    unsigned int r = v.u + 0x7fffu + ((v.u >> 16) & 1u);  // RNE
    return (unsigned short)(r >> 16);
}

__device__ __forceinline__ float wave_sum(float v) {
    #pragma unroll
    for (int off = 32; off; off >>= 1) v += __shfl_xor(v, off, 64);
    return v;
}

__device__ __forceinline__ float wave_max(float v) {
    #pragma unroll
    for (int off = 32; off; off >>= 1) v = fmaxf(v, __shfl_xor(v, off, 64));
    return v;
}

__device__ __forceinline__ float read_f(const void* src, int i, int isBf16) {
    if (isBf16) return bf2f(((const unsigned short*)src)[i]);
    return ((const float*)src)[i];
}

// Inline x-dtype sniff: every block reads the SAME x[0:1024] words (4KB,
// L2-hit) -> all blocks reach the same verdict deterministically.
__device__ __forceinline__ int sniff_x(const void* xraw, int tid, int* fS) {
    if (tid == 0) *fS = 1;
    __syncthreads();
    int bad = 0;
    const unsigned int* xw = (const unsigned int*)xraw;
    #pragma unroll
    for (int q = 0; q < 4; q++) {
        unsigned int w = xw[(tid & 255) * 4 + q];
        unsigned int e0 = (w >> 7) & 0xffu;
        unsigned int e1 = (w >> 23) & 0xffu;
        if (e0 >= 0x90u || e1 >= 0x90u) bad = 1;
    }
    if (bad) *fS = 0;
    __syncthreads();
    return *fS;
}

// ---------------- prep: build_nbr + all conversions in ONE launch -----------
// NOTE (R14 post-mortem): do NOT fuse the l2 split-K reduction into l2_gemm
// via global atomicAdd — cross-XCD f32 atomics resolve at the fabric
// coherence point (per-XCD L2s non-coherent) and cost +16.5 us vs the
// L2-resident Cp2 partials round-trip used here.
// NOTE (R4-R6 this session): persistent mega-kernel with device-scope spin
// barriers is ~100x too slow on MI355X: RMW-poll serializes at the coherence
// point (~400 us); relaxed-load poll reads stale per-XCD L2 lines until
// eviction (~380 us, 31 ms outlier). Multi-launch is the correct structure.
__global__ __launch_bounds__(256) void prep(const unsigned char* __restrict__ adj,
                                            const void* __restrict__ x,
                                            const void* __restrict__ W1,
                                            const void* __restrict__ W2,
                                            const void* __restrict__ a1s,
                                            const void* __restrict__ a1d,
                                            const void* __restrict__ a2s,
                                            const void* __restrict__ a2d,
                                            int* __restrict__ nbr,
                                            int* __restrict__ deg,
                                            unsigned short* __restrict__ W1bth,
                                            unsigned short* __restrict__ W1btl,
                                            float* __restrict__ W2p,
                                            float* __restrict__ a1sf,
                                            float* __restrict__ a1df,
                                            float* __restrict__ a2sf,
                                            float* __restrict__ a2df) {
    __shared__ int cnt;
    __shared__ int fS;
    int t = threadIdx.x;
    int blk = blockIdx.x;

    if (blk < NN) {
        // ---- build_nbr path; adj elem-size sniff: byte t*(NN+1) (valid in
        // both layouts). Byte-bool: diagonal -> all 1. Int32: t%4!=0 hits a
        // zero byte-lane of a 0/1 word -> 0.
        if (t == 0) { cnt = 0; fS = 1; }
        __syncthreads();
        if (adj[(size_t)t * (NN + 1)] == 0) fS = 0;  // benign race
        __syncthreads();
        int isByte = fS;
        int i = blk;
        if (isByte) {
            uint4 v = ((const uint4*)(adj + (size_t)i * NN))[t];
            unsigned int u[4] = { v.x, v.y, v.z, v.w };
            int base = t * 16;
            #pragma unroll
            for (int q = 0; q < 4; q++) {
                #pragma unroll
                for (int b = 0; b < 4; b++) {
                    if ((u[q] >> (8 * b)) & 0xffu) {
                        int p = atomicAdd(&cnt, 1);
                        if (p < MAXDEG) nbr[(size_t)i * MAXDEG + p] = base + q * 4 + b;
                    }
                }
            }
        } else {
            const int4* row = (const int4*)((const int*)adj + (size_t)i * NN);
            #pragma unroll
            for (int q = 0; q < 4; q++) {
                int idx4 = q * 256 + t;
                int4 v = row[idx4];
                int base = idx4 * 4;
                if (v.x) { int p = atomicAdd(&cnt, 1); if (p < MAXDEG) nbr[(size_t)i * MAXDEG + p] = base; }
                if (v.y) { int p = atomicAdd(&cnt, 1); if (p < MAXDEG) nbr[(size_t)i * MAXDEG + p] = base + 1; }
                if (v.z) { int p = atomicAdd(&cnt, 1); if (p < MAXDEG) nbr[(size_t)i * MAXDEG + p] = base + 2; }
                if (v.w) { int p = atomicAdd(&cnt, 1); if (p < MAXDEG) nbr[(size_t)i * MAXDEG + p] = base + 3; }
            }
        }
        __syncthreads();
        if (t == 0) deg[i] = min(cnt, MAXDEG);
        return;
    }

    int bf = sniff_x(x, t, &fS);

    if (blk < NN + 64) {
        // ---- W1 transpose path: thread owns 16 consecutive OUTPUT elems
        // (32B coalesced store per array); reads are stride-DD, L2-resident.
        int b = blk - NN;                       // 0..63
        int ob = b * 4096 + t * 16;             // output elem base (262,144 tot)
        int row = ob >> 9;                      // hd*64 + d
        int f0 = ob & 511;
        int hd = row >> 6, d = row & 63;
        unsigned short hi[16], lo[16];
        #pragma unroll
        for (int q = 0; q < 16; q++) {
            float v = read_f(W1, (hd * FF + f0 + q) * DD + d, bf);
            unsigned short h16 = f2bf(v);
            hi[q] = h16;
            lo[q] = f2bf(v - bf2f(h16));
        }
        #pragma unroll
        for (int q = 0; q < 16; q++) {
            W1bth[(size_t)row * FF + f0 + q] = hi[q];
            W1btl[(size_t)row * FF + f0 + q] = lo[q];
        }
        return;
    }

    // ---- small tensors: W2p (zero-padded), a-vectors
    int i = (blk - NN - 64) * 256 + t;
    const int nW2p = HD * CP;          // 32,768
    const int nA1 = HD;                // 512
    if (i < nW2p) {
        int k = i / CP, c = i % CP;
        W2p[i] = (c < CC) ? read_f(W2, k * CC + c, bf) : 0.f;
        return;
    }
    i -= nW2p;
    if (i < nA1) { a1sf[i] = read_f(a1s, i, bf); return; }
    i -= nA1;
    if (i < nA1) { a1df[i] = read_f(a1d, i, bf); return; }
    i -= nA1;
    if (i < CC) { a2sf[i] = read_f(a2s, i, bf); return; }
    i -= CC;
    if (i < CC) { a2df[i] = read_f(a2d, i, bf); return; }
}

// ------ l1 GEMM via MFMA bf16x3, native x; si/sj via LDS (no atomics) -------
__global__ __launch_bounds__(256) void l1_gemm(const void* __restrict__ xraw,
                                               const unsigned short* __restrict__ W1bth,
                                               const unsigned short* __restrict__ W1btl,
                                               const float* __restrict__ a1sf,
                                               const float* __restrict__ a1df,
                                               unsigned short* __restrict__ hb,
                                               float* __restrict__ si,
                                               float* __restrict__ sj) {
    __shared__ __align__(16) unsigned short Ah[64][40];
    __shared__ __align__(16) unsigned short Al[64][40];
    __shared__ __align__(16) unsigned short Bh[64][40];
    __shared__ __align__(16) unsigned short Bl[64][40];
    __shared__ int fS;

    int bm = blockIdx.x, hd = blockIdx.y;
    int tid = threadIdx.x;
    int isBf16 = sniff_x(xraw, tid, &fS);

    int wave = tid >> 6, lane = tid & 63;
    int wm = wave >> 1, wn = wave & 1;
    int lr = lane & 15, lg = lane >> 4;
    int srow = tid >> 2;
    int sseg = (tid & 3) * 8;

    const unsigned short* wAp = W1bth + (size_t)(hd * 64 + srow) * FF + sseg;
    const unsigned short* wBp = W1btl + (size_t)(hd * 64 + srow) * FF + sseg;

    f32x4 acc[2][2];
    #pragma unroll
    for (int r = 0; r < 2; r++)
        #pragma unroll
        for (int c = 0; c < 2; c++) acc[r][c] = (f32x4){0.f, 0.f, 0.f, 0.f};

    if (isBf16) {
        const unsigned short* xp = (const unsigned short*)xraw
                                 + (size_t)(bm * 64 + srow) * FF + sseg;
        uint4 ra = *(const uint4*)xp;
        uint4 rb = *(const uint4*)wAp;
        for (int kk = 0; kk < FF; kk += 32) {
            __syncthreads();
            *(uint4*)&Ah[srow][sseg] = ra;
            *(uint4*)&Bh[srow][sseg] = rb;
            __syncthreads();
            int kn = (kk + 32 < FF) ? kk + 32 : kk;
            ra = *(const uint4*)(xp + kn);
            rb = *(const uint4*)(wAp + kn);
            bf16x8 a0 = *(const bf16x8*)&Ah[wm * 32 + lr][lg * 8];
            bf16x8 a1 = *(const bf16x8*)&Ah[wm * 32 + 16 + lr][lg * 8];
            bf16x8 b0 = *(const bf16x8*)&Bh[wn * 32 + lr][lg * 8];
            bf16x8 b1 = *(const bf16x8*)&Bh[wn * 32 + 16 + lr][lg * 8];
            acc[0][0] = __builtin_amdgcn_mfma_f32_16x16x32_bf16(a0, b0, acc[0][0], 0, 0, 0);
            acc[0][1] = __builtin_amdgcn_mfma_f32_16x16x32_bf16(a0, b1, acc[0][1], 0, 0, 0);
            acc[1][0] = __builtin_amdgcn_mfma_f32_16x16x32_bf16(a1, b0, acc[1][0], 0, 0, 0);
            acc[1][1] = __builtin_amdgcn_mfma_f32_16x16x32_bf16(a1, b1, acc[1][1], 0, 0, 0);
        }
    } else {
        const float* xp = (const float*)xraw + (size_t)(bm * 64 + srow) * FF + sseg;
        float4 ra0 = *(const float4*)xp;
        float4 ra1 = *(const float4*)(xp + 4);
        uint4 rbh = *(const uint4*)wAp;
        uint4 rbl = *(const uint4*)wBp;
        for (int kk = 0; kk < FF; kk += 32) {
            __syncthreads();
            union { unsigned short s[8]; uint4 v; } uh, ul;
            float fv[8] = { ra0.x, ra0.y, ra0.z, ra0.w, ra1.x, ra1.y, ra1.z, ra1.w };
            #pragma unroll
            for (int q = 0; q < 8; q++) {
                unsigned short h16 = f2bf(fv[q]);
                uh.s[q] = h16;
                ul.s[q] = f2bf(fv[q] - bf2f(h16));
            }
            *(uint4*)&Ah[srow][sseg] = uh.v;
            *(uint4*)&Al[srow][sseg] = ul.v;
            *(uint4*)&Bh[srow][sseg] = rbh;
            *(uint4*)&Bl[srow][sseg] = rbl;
            __syncthreads();
            int kn = (kk + 32 < FF) ? kk + 32 : kk;
            ra0 = *(const float4*)(xp + kn);
            ra1 = *(const float4*)(xp + kn + 4);
            rbh = *(const uint4*)(wAp + kn);
            rbl = *(const uint4*)(wBp + kn);

            bf16x8 a_h0 = *(const bf16x8*)&Ah[wm * 32 + lr][lg * 8];
            bf16x8 a_h1 = *(const bf16x8*)&Ah[wm * 32 + 16 + lr][lg * 8];
            bf16x8 a_l0 = *(const bf16x8*)&Al[wm * 32 + lr][lg * 8];
            bf16x8 a_l1 = *(const bf16x8*)&Al[wm * 32 + 16 + lr][lg * 8];
            bf16x8 b_h0 = *(const bf16x8*)&Bh[wn * 32 + lr][lg * 8];
            bf16x8 b_h1 = *(const bf16x8*)&Bh[wn * 32 + 16 + lr][lg * 8];
            bf16x8 b_l0 = *(const bf16x8*)&Bl[wn * 32 + lr][lg * 8];
            bf16x8 b_l1 = *(const bf16x8*)&Bl[wn * 32 + 16 + lr][lg * 8];

            acc[0][0] = __builtin_amdgcn_mfma_f32_16x16x32_bf16(a_h0, b_h0, acc[0][0], 0, 0, 0);
            acc[0][1] = __builtin_amdgcn_mfma_f32_16x16x32_bf16(a_h0, b_h1, acc[0][1], 0, 0, 0);
            acc[1][0] = __builtin_amdgcn_mfma_f32_16x16x32_bf16(a_h1, b_h0, acc[1][0], 0, 0, 0);
            acc[1][1] = __builtin_amdgcn_mfma_f32_16x16x32_bf16(a_h1, b_h1, acc[1][1], 0, 0, 0);
            acc[0][0] = __builtin_amdgcn_mfma_f32_16x16x32_bf16(a_h0, b_l0, acc[0][0], 0, 0, 0);
            acc[0][1] = __builtin_amdgcn_mfma_f32_16x16x32_bf16(a_h0, b_l1, acc[0][1], 0, 0, 0);
            acc[1][0] = __builtin_amdgcn_mfma_f32_16x16x32_bf16(a_h1, b_l0, acc[1][0], 0, 0, 0);
            acc[1][1] = __builtin_amdgcn_mfma_f32_16x16x32_bf16(a_h1, b_l1, acc[1][1], 0, 0, 0);
            acc[0][0] = __builtin_amdgcn_mfma_f32_16x16x32_bf16(a_l0, b_h0, acc[0][0], 0, 0, 0);
            acc[0][1] = __builtin_amdgcn_mfma_f32_16x16x32_bf16(a_l0, b_h1, acc[0][1], 0, 0, 0);
            acc[1][0] = __builtin_amdgcn_mfma_f32_16x16x32_bf16(a_l1, b_h0, acc[1][0], 0, 0, 0);
            acc[1][1] = __builtin_amdgcn_mfma_f32_16x16x32_bf16(a_l1, b_h1, acc[1][1], 0, 0, 0);
        }
    }

    // epilogue: h writes + si/sj partials reduced across the two wn-waves
    // via LDS (reuse Ah as float scratch; no global atomics).
    float adv[2], asv[2];
    #pragma unroll
    for (int fc = 0; fc < 2; fc++) {
        adv[fc] = a1df[hd * DD + wn * 32 + fc * 16 + lr];
        asv[fc] = a1sf[hd * DD + wn * 32 + fc * 16 + lr];
    }
    float pdv[2][4], psv[2][4];
    #pragma unroll
    for (int fr = 0; fr < 2; fr++) {
        #pragma unroll
        for (int q = 0; q < 4; q++) {
            int row = bm * 64 + wm * 32 + fr * 16 + lg * 4 + q;
            int colb = hd * 64 + wn * 32;
            hb[(size_t)row * HD + colb + lr] = f2bf(acc[fr][0][q]);
            hb[(size_t)row * HD + colb + 16 + lr] = f2bf(acc[fr][1][q]);
            float pd = acc[fr][0][q] * adv[0] + acc[fr][1][q] * adv[1];
            float ps = acc[fr][0][q] * asv[0] + acc[fr][1][q] * asv[1];
            #pragma unroll
            for (int off = 1; off < 16; off <<= 1) {
                pd += __shfl_xor(pd, off, 64);
                ps += __shfl_xor(ps, off, 64);
            }
            pdv[fr][q] = pd;
            psv[fr][q] = ps;
        }
    }
    float* sred = (float*)&Ah[0][0];  // 64 rows x {si,sj} = 512B
    __syncthreads();
    if (wn == 0 && lr == 0) {
        #pragma unroll
        for (int fr = 0; fr < 2; fr++)
            #pragma unroll
            for (int q = 0; q < 4; q++) {
                int rl = wm * 32 + fr * 16 + lg * 4 + q;
                sred[rl * 2] = pdv[fr][q];
                sred[rl * 2 + 1] = psv[fr][q];
            }
    }
    __syncthreads();
    if (wn == 1 && lr == 0) {
        #pragma unroll
        for (int fr = 0; fr < 2; fr++)
            #pragma unroll
            for (int q = 0; q < 4; q++) {
                int rl = wm * 32 + fr * 16 + lg * 4 + q;
                int row = bm * 64 + rl;
                si[hd * NN + row] = sred[rl * 2] + pdv[fr][q];
                sj[hd * NN + row] = sred[rl * 2 + 1] + psv[fr][q];
            }
    }
}

// -------- layer-1 attention: 256 thr/node, uint (2xbf16) gather -------------
__global__ __launch_bounds__(256) void l1_attn(const int* __restrict__ nbr,
                                               const int* __restrict__ deg,
                                               const unsigned short* __restrict__ hb,
                                               const float* __restrict__ si,
                                               const float* __restrict__ sj,
                                               float* __restrict__ x2) {
    int i = blockIdx.x;
    int tid = threadIdx.x;
    int wave = tid >> 6, lane = tid & 63;
    int d = deg[i];
    __shared__ int js[MAXDEG];
    __shared__ float wls[HH][MAXDEG];
    for (int k = tid; k < d; k += 256) js[k] = nbr[(size_t)i * MAXDEG + k];
    __syncthreads();

    int hd = wave * 2 + (lane >> 5);
    int l32 = lane & 31;
    float sii = si[hd * NN + i];
    const float* sjh = sj + (size_t)hd * NN;
    float m = -1e30f;
    for (int k = l32; k < d; k += 32) {
        float sc = sii + sjh[js[k]];
        sc = sc > 0.f ? sc : ALPHA * sc;
        wls[hd][k] = sc;
        m = fmaxf(m, sc);
    }
    #pragma unroll
    for (int off = 16; off; off >>= 1) m = fmaxf(m, __shfl_xor(m, off, 64));
    float s = 0.f;
    for (int k = l32; k < d; k += 32) {
        float e = expf(wls[hd][k] - m);
        wls[hd][k] = e;
        s += e;
    }
    #pragma unroll
    for (int off = 16; off; off >>= 1) s += __shfl_xor(s, off, 64);
    float inv = 1.f / fmaxf(s, 1e-30f);
    for (int k = l32; k < d; k += 32) wls[hd][k] *= inv;
    __syncthreads();

    const unsigned int* hu = (const unsigned int*)hb;
    const float* wl = wls[tid >> 5];
    float a0 = 0.f, a1 = 0.f;
    int k = 0;
    for (; k + 4 <= d; k += 4) {
        unsigned int v0 = hu[(size_t)js[k] * 256 + tid];
        unsigned int v1 = hu[(size_t)js[k + 1] * 256 + tid];
        unsigned int v2 = hu[(size_t)js[k + 2] * 256 + tid];
        unsigned int v3 = hu[(size_t)js[k + 3] * 256 + tid];
        float w0 = wl[k], w1 = wl[k + 1], w2 = wl[k + 2], w3 = wl[k + 3];
        a0 = fmaf(w0, bf2f((unsigned short)v0), a0);
        a1 = fmaf(w0, bf2f((unsigned short)(v0 >> 16)), a1);
        a0 = fmaf(w1, bf2f((unsigned short)v1), a0);
        a1 = fmaf(w1, bf2f((unsigned short)(v1 >> 16)), a1);
        a0 = fmaf(w2, bf2f((unsigned short)v2), a0);
        a1 = fmaf(w2, bf2f((unsigned short)(v2 >> 16)), a1);
        a0 = fmaf(w3, bf2f((unsigned short)v3), a0);
        a1 = fmaf(w3, bf2f((unsigned short)(v3 >> 16)), a1);
    }
    for (; k < d; k++) {
        unsigned int v = hu[(size_t)js[k] * 256 + tid];
        float w = wl[k];
        a0 = fmaf(w, bf2f((unsigned short)v), a0);
        a1 = fmaf(w, bf2f((unsigned short)(v >> 16)), a1);
    }
    float r0 = a0 > 0.f ? a0 : expm1f(a0);  // ELU fused
    float r1 = a1 > 0.f ? a1 : expm1f(a1);
    *(float2*)(x2 + (size_t)i * HD + tid * 2) = make_float2(r0, r1);
}

// ------ generic LDS-tiled split-K GEMM body (l2) ----------------------------
template <int KHs, int Nb>
__device__ __forceinline__ void gemm_body(const float* __restrict__ Ap,
                                          const float* __restrict__ Bp,
                                          float* __restrict__ Co,
                                          int tid, int bm) {
    __shared__ float As[BK][BM + 4];
    __shared__ float Bs[BK][BN + 4];
    int tm = tid >> 4, tn = tid & 15;
    int m0 = tm * 4, n0 = tn * 4;
    int ar = tid >> 2, ak = (tid & 3) * 4;
    int bk = tid >> 4, bq = (tid & 15) * 4;

    float acc[4][4];
    #pragma unroll
    for (int r = 0; r < 4; r++)
        #pragma unroll
        for (int c = 0; c < 4; c++) acc[r][c] = 0.f;

    const float* Ar = Ap + (size_t)ar * FF;
    float4 av = *(const float4*)(Ar + ak);
    float4 bv = *(const float4*)(Bp + (size_t)bk * Nb + bq);

    for (int k0 = 0; k0 < KHs; k0 += BK) {
        __syncthreads();
        As[ak + 0][ar] = av.x;
        As[ak + 1][ar] = av.y;
        As[ak + 2][ar] = av.z;
        As[ak + 3][ar] = av.w;
        *(float4*)&Bs[bk][bq] = bv;
        __syncthreads();

        int kn = (k0 + BK < KHs) ? k0 + BK : k0;
        av = *(const float4*)(Ar + kn + ak);
        bv = *(const float4*)(Bp + (size_t)(kn + bk) * Nb + bq);

        #pragma unroll
        for (int k = 0; k < BK; k++) {
            float4 a = *(const float4*)&As[k][m0];
            float4 b = *(const float4*)&Bs[k][n0];
            acc[0][0] = fmaf(a.x, b.x, acc[0][0]);
            acc[0][1] = fmaf(a.x, b.y, acc[0][1]);
            acc[0][2] = fmaf(a.x, b.z, acc[0][2]);
            acc[0][3] = fmaf(a.x, b.w, acc[0][3]);
            acc[1][0] = fmaf(a.y, b.x, acc[1][0]);
            acc[1][1] = fmaf(a.y, b.y, acc[1][1]);
            acc[1][2] = fmaf(a.y, b.z, acc[1][2]);
            acc[1][3] = fmaf(a.y, b.w, acc[1][3]);
            acc[2][0] = fmaf(a.z, b.x, acc[2][0]);
            acc[2][1] = fmaf(a.z, b.y, acc[2][1]);
            acc[2][2] = fmaf(a.z, b.z, acc[2][2]);
            acc[2][3] = fmaf(a.z, b.w, acc[2][3]);
            acc[3][0] = fmaf(a.w, b.x, acc[3][0]);
            acc[3][1] = fmaf(a.w, b.y, acc[3][1]);
            acc[3][2] = fmaf(a.w, b.z, acc[3][2]);
            acc[3][3] = fmaf(a.w, b.w, acc[3][3]);
        }
    }

    #pragma unroll
    for (int r = 0; r < 4; r++) {
        float4 v = make_float4(acc[r][0], acc[r][1], acc[r][2], acc[r][3]);
        *(float4*)(Co + (size_t)(bm * BM + m0 + r) * Nb + n0) = v;
    }
}

// ------ l2 GEMM: Cp2[sk] = x2 @ W2p  (N = 64 padded) ------------------------
__global__ __launch_bounds__(256) void l2_gemm(const float* __restrict__ x2,
                                               const float* __restrict__ W2p,
                                               float* __restrict__ Cp2) {
    int bm = blockIdx.x, sk = blockIdx.z;
    gemm_body<KH2, CP>(x2 + (size_t)bm * BM * FF + sk * KH2,
                       W2p + (size_t)(sk * KH2) * CP,
                       Cp2 + (size_t)sk * NN * CP,
                       threadIdx.x, bm);
}

// ------ l2 post: h2 = sum_sk Cp2[sk], d1/d2 wave reductions -----------------
__global__ __launch_bounds__(64) void l2_post(const float* __restrict__ Cp2,
                                              const float* __restrict__ a2sf,
                                              const float* __restrict__ a2df,
                                              float* __restrict__ h2,
                                              float* __restrict__ d1,
                                              float* __restrict__ d2) {
    int n = blockIdx.x, c = threadIdx.x;
    float v = 0.f;
    #pragma unroll
    for (int sk = 0; sk < SK2; sk++)
        v += Cp2[(size_t)sk * NN * CP + (size_t)n * CP + c];
    if (c < CC) h2[(size_t)n * CC + c] = v;
    float pd = wave_sum((c < CC) ? v * a2df[c] : 0.f);
    float ps = wave_sum((c < CC) ? v * a2sf[c] : 0.f);
    if (c == 0) {
        d1[n] = pd;
        d2[n] = ps;
    }
}

// -------- layer-2 attention: 4 nodes per 256-thread block, wave = node ------
__global__ __launch_bounds__(256) void l2_attn(const int* __restrict__ nbr,
                                               const int* __restrict__ deg,
                                               const float* __restrict__ h2,
                                               const float* __restrict__ d1,
                                               const float* __restrict__ d2,
                                               float* __restrict__ out) {
    int w = threadIdx.x >> 6, lane = threadIdx.x & 63;
    int i = blockIdx.x * 4 + w;
    int d = deg[i];
    __shared__ int js[4][MAXDEG];
    __shared__ float wls[4][MAXDEG];
    for (int k = lane; k < d; k += 64) js[w][k] = nbr[(size_t)i * MAXDEG + k];

    float sii = d1[i];
    float m = -1e30f;
    for (int k = lane; k < d; k += 64) {
        float sc = sii + d2[js[w][k]];
        sc = sc > 0.f ? sc : ALPHA * sc;
        wls[w][k] = sc;
        m = fmaxf(m, sc);
    }
    m = wave_max(m);
    float s = 0.f;
    for (int k = lane; k < d; k += 64) {
        float e = expf(wls[w][k] - m);
        wls[w][k] = e;
        s += e;
    }
    s = fmaxf(wave_sum(s), 1e-30f);

    int c = lane;
    if (c < CC) {
        float acc = 0.f;
        int k = 0;
        for (; k + 4 <= d; k += 4) {
            float v0 = h2[(size_t)js[w][k] * CC + c];
            float v1 = h2[(size_t)js[w][k + 1] * CC + c];
            float v2 = h2[(size_t)js[w][k + 2] * CC + c];
            float v3 = h2[(size_t)js[w][k + 3] * CC + c];
            acc = fmaf(wls[w][k], v0, acc);
            acc = fmaf(wls[w][k + 1], v1, acc);
            acc = fmaf(wls[w][k + 2], v2, acc);
            acc = fmaf(wls[w][k + 3], v3, acc);
        }
        for (; k < d; k++)
            acc = fmaf(wls[w][k], h2[(size_t)js[w][k] * CC + c], acc);
        out[(size_t)i * CC + c] = acc / s;
    }
}

extern "C" void kernel_launch(void* const* d_in, const int* in_sizes, int n_in,
                              void* d_out, int out_size, void* d_ws, size_t ws_size,
                              hipStream_t stream) {
    const void* x   = d_in[0];
    const unsigned char* adj = (const unsigned char*)d_in[1];
    const void* W1  = d_in[2];
    const void* a1s = d_in[3];  // a1_src
    const void* a1d = d_in[4];  // a1_dst
    const void* W2  = d_in[5];
    const void* a2s = d_in[6];
    const void* a2d = d_in[7];

    char* ws = (char*)d_ws;
    int*   nbr   = (int*)(ws + 0);                        // 2,097,152
    int*   deg   = (int*)(ws + 2097152);                  // 16,384
    float* si    = (float*)(ws + 2113536);                // 131,072
    float* sj    = (float*)(ws + 2244608);                // 131,072
    unsigned short* W1bth = (unsigned short*)(ws + 2375680);  // 524,288
    unsigned short* W1btl = (unsigned short*)(ws + 2899968);  // 524,288
    float* W2p   = (float*)(ws + 3424256);                // 131,072
    float* a1sf  = (float*)(ws + 3555328);                // 2,048
    float* a1df  = (float*)(ws + 3557376);                // 2,048
    float* a2sf  = (float*)(ws + 3559424);                // 256
    float* a2df  = (float*)(ws + 3559680);                // 256
    unsigned short* hb = (unsigned short*)(ws + 3559936); // 4,194,304 [N][H*D] bf16
    float* x2    = (float*)(ws + 7754240);                // 8,388,608
    float* h2    = (float*)(ws + 16142848);               // 655,360
    float* d1    = (float*)(ws + 16798208);               // 16,384
    float* d2    = (float*)(ws + 16814592);               // 16,384
    float* Cp2   = (float*)(ws + 16830976);               // 8,388,608
    // total ~25.2 MB

    // prep grid: 4096 nbr rows + 64 W1-transpose blocks + 133 small blocks
    const int nSmall = HD * CP + 2 * HD + 2 * CC;  // 33,872
    const int prepGrid = NN + 64 + (nSmall + 255) / 256;
    hipLaunchKernelGGL(prep, dim3(prepGrid), dim3(256), 0, stream,
                       adj, x, W1, W2, a1s, a1d, a2s, a2d,
                       nbr, deg, W1bth, W1btl, W2p, a1sf, a1df, a2sf, a2df);

    hipLaunchKernelGGL(l1_gemm, dim3(NN / 64, HH), dim3(256), 0, stream,
                       x, W1bth, W1btl, a1sf, a1df, hb, si, sj);
    hipLaunchKernelGGL(l1_attn, dim3(NN), dim3(256), 0, stream,
                       nbr, deg, hb, si, sj, x2);
    hipLaunchKernelGGL(l2_gemm, dim3(NN / BM, 1, SK2), dim3(256), 0, stream,
                       x2, W2p, Cp2);
    hipLaunchKernelGGL(l2_post, dim3(NN), dim3(64), 0, stream,
                       Cp2, a2sf, a2df, h2, d1, d2);
    hipLaunchKernelGGL(l2_attn, dim3(NN / 4), dim3(256), 0, stream,
                       nbr, deg, h2, d1, d2, (float*)d_out);
}